// Round 4
// baseline (416.475 us; speedup 1.0000x reference)
//
#include <hip/hip_runtime.h>

// Problem: SphereConv2DEXP — grid_sample(bilinear) + 3x3/stride-3 conv
//   == implicit GEMM: M=131072, N=256, K=1152.
//
// R4: the gather was address-bound (TA path: 8 scattered 8B loads -> 4 A vals).
//  (a) x transposed NCHW -> NHWC **f16** (32 MB ws): each bilinear tap is now
//      channel-contiguous -> 4 scattered 16B loads yield 8 A values (4x fewer
//      scattered addresses).
//  (b) whole GEMM in f16 (10-bit mantissa > bf16's 7): mfma_f32_16x16x32_f16,
//      same frag layout, better absmax.
//  (c) tap tables in LDS as [ij][sp] -> in-loop reads lane-contiguous
//      (conflict-free; was the main SQ_LDS_BANK_CONFLICT source).
//  (d) role-split staging: waves 0-3 gather A, waves 4-7 stream B.
//  (e) packed-f16 interpolation (v_pk ops), chunked XCD swizzle (2048%8==0).
// Keeps R3's ci-outer/ij-inner K order + double-buffered one-barrier pipeline.

#define Hh   128
#define Ww   256
#define HWp  (Hh*Ww)        // 32768 per-channel image size
#define CIN  128
#define COUT 256
#define KTOT 1152
#define NPTS (384*768)      // 294912 grid points
#define BM   64
#define BN   256
#define BK   32
#define NKS  (KTOT/BK)      // 36 K-steps

typedef __attribute__((ext_vector_type(8))) _Float16 f16x8;
typedef __attribute__((ext_vector_type(4))) float    f32x4;

__device__ __forceinline__ f16x8 bcast8(float f) {
    _Float16 h = (_Float16)f;
    f16x8 v;
#pragma unroll
    for (int i = 0; i < 8; ++i) v[i] = h;
    return v;
}

// ---------------------------------------------------------------------------
// Prep kernel: blocks [0,1152) bilinear tap table; [1152,2304) weights -> f16
// retiled wt2[ks][n][kk] (K order: ks -> ij = ks%9, ci = (ks/9)*32 + kk);
// [2304,10496) x NCHW -> NHWC f16 transpose.
// ---------------------------------------------------------------------------
__global__ void prep(const float* __restrict__ grid, const float* __restrict__ w,
                     const float* __restrict__ x,
                     int2* __restrict__ tI, float4* __restrict__ tW,
                     _Float16* __restrict__ wt2, _Float16* __restrict__ xt) {
    const int bid = blockIdx.x;
    const int t   = threadIdx.x;
    if (bid < NPTS / 256) {
        int g = bid * 256 + t;
        int hh = g / 768, ww = g - hh * 768;
        int ho = hh / 3, ii = hh - 3 * ho;
        int wo = ww / 3, jj = ww - 3 * wo;

        float gx = grid[2 * g + 0];
        float gy = grid[2 * g + 1];
        float ix = ((gx + 1.0f) * (float)Ww - 1.0f) * 0.5f;
        float iy = ((gy + 1.0f) * (float)Hh - 1.0f) * 0.5f;
        float x0f = floorf(ix), y0f = floorf(iy);
        int x0 = (int)x0f, y0 = (int)y0f;
        float wx1 = ix - x0f, wx0 = 1.0f - wx1;
        float wy1 = iy - y0f, wy0 = 1.0f - wy1;

        float wyt = (y0 >= 0 && y0 < Hh) ? wy0 : 0.0f;
        float wyb = (y0 + 1 >= 0 && y0 + 1 < Hh) ? wy1 : 0.0f;
        int r0 = min(max(y0, 0), Hh - 1);
        int r1 = min(max(y0 + 1, 0), Hh - 1);

        int xb; float cw0, cw1;
        if (x0 < 0)            { xb = 0;      cw0 = wx1; cw1 = 0.0f; }
        else if (x0 > Ww - 2)  { xb = Ww - 2; cw0 = 0.0f; cw1 = wx0; }
        else                   { xb = x0;     cw0 = wx0; cw1 = wx1; }

        int e = (ho * Ww + wo) * 9 + ii * 3 + jj;   // (sp, ij) order
        tI[e] = make_int2(r0 * Ww + xb, r1 * Ww + xb);
        tW[e] = make_float4(cw0 * wyt, cw1 * wyt, cw0 * wyb, cw1 * wyb);
    } else if (bid < 2 * (NPTS / 256)) {
        int o = (bid - NPTS / 256) * 256 + t;       // NKS*COUT*BK = 294912
        int kk = o & (BK - 1);
        int n  = (o >> 5) & (COUT - 1);
        int ks = o >> 13;
        int ij = ks % 9;
        int ci = (ks / 9) * 32 + kk;
        wt2[o] = (_Float16)w[n * KTOT + ci * 9 + ij];
    } else {
        // transpose: r enumerates (b, cg, sp); lanes -> consecutive sp (coalesced)
        int r  = (bid - 2 * (NPTS / 256)) * 256 + t;    // 4*16*32768 total
        int sp = r & (HWp - 1);
        int cg = (r >> 15) & 15;
        int b  = r >> 19;
        const float* src = x + ((size_t)(b * CIN + cg * 8)) * HWp + sp;
        f16x8 v;
#pragma unroll
        for (int j = 0; j < 8; ++j) v[j] = (_Float16)src[(size_t)j * HWp];
        *(f16x8*)&xt[((size_t)(b * HWp + sp)) * CIN + cg * 8] = v;
    }
}

// ---------------------------------------------------------------------------
// Fused gather + f16 MFMA GEMM, double-buffered, one barrier per K-step.
// Block: 512 thr (8 waves, 2x4), tile BM=64 x BN=256, K-step 32 channels.
// Wave tile 32x64 = 2x4 frags of mfma_f32_16x16x32_f16.
// Waves 0-3 stage A (gather from NHWC x_t), waves 4-7 stage B.
// Step ks: ij = ks%9 (fixed), channels (ks/9)*32 .. +31.
// ---------------------------------------------------------------------------
__global__ __launch_bounds__(512, 4) void sphconv_gemm(
    const _Float16* __restrict__ xt, const _Float16* __restrict__ wt2,
    const float* __restrict__ bias, const int2* __restrict__ tI,
    const float4* __restrict__ tW, float* __restrict__ out) {

    __shared__ int2   sTI[9 * BM];                       //  4608 B  [ij][sp]
    __shared__ float4 sTW[9 * BM];                       //  9216 B  [ij][sp]
    __shared__ __align__(16) _Float16 sA[2][BM * 40];    // 2x 5120 B
    __shared__ __align__(16) _Float16 sB[2][BN * 40];    // 2x20480 B -> 65024 total

    const int t = threadIdx.x;
    // chunked XCD swizzle: 2048 blocks, 8 XCDs, bijective (2048 % 8 == 0)
    const int bid = blockIdx.x;
    const int swz = (bid & 7) * 256 + (bid >> 3);
    const int m0  = swz * BM;
    const int b   = m0 >> 15;           // / 32768
    const int sp0 = m0 & (HWp - 1);
    const _Float16* xb_ = xt + (size_t)b * (HWp * CIN);

    // tap table, transposed to [ij][sp] so in-loop lane reads are contiguous
    for (int e = t; e < 9 * BM; e += 512) {
        int r = e & (BM - 1), ij = e >> 6;
        sTI[e] = tI[(sp0 + r) * 9 + ij];
        sTW[e] = tW[(sp0 + r) * 9 + ij];
    }

    const int lane = t & 63;
    const int wid  = t >> 6;
    const int wrow = wid >> 2;          // 0..1 -> m offset 32*wrow
    const int wcol = wid & 3;           // 0..3 -> n offset 64*wcol
    const int quad = lane >> 4;         // 0..3
    const int l16  = lane & 15;

    const bool isA = (t < 256);
    const int  mr  = t & 63;            // A staging row
    const int  chb = ((t >> 6) & 3) * 8;// A channel sub-base (0,8,16,24)
    const int  u   = t - 256;           // B staging row (t>=256)

    f32x4 acc[2][4];
#pragma unroll
    for (int r = 0; r < 2; ++r)
#pragma unroll
        for (int c = 0; c < 4; ++c) {
            f32x4 z = {0.0f, 0.0f, 0.0f, 0.0f};
            acc[r][c] = z;
        }

    __syncthreads();  // table ready

    // ---- prologue: load step 0 into regs, stage buffer 0 ----
    f16x8 p00, p01, p10, p11;           // A taps (channel-contiguous)
    float4 wv;
    f16x8 b0v, b1v, b2v, b3v;           // B chunk
    if (isA) {
        const int2 o = sTI[mr];         // ij=0
        wv = sTW[mr];
        const _Float16* p = xb_ + (size_t)o.x * CIN + chb;
        const _Float16* q = xb_ + (size_t)o.y * CIN + chb;
        p00 = *(const f16x8*)p;  p01 = *(const f16x8*)(p + CIN);
        p10 = *(const f16x8*)q;  p11 = *(const f16x8*)(q + CIN);
        f16x8 av = p00 * bcast8(wv.x) + p01 * bcast8(wv.y)
                 + p10 * bcast8(wv.z) + p11 * bcast8(wv.w);
        *(f16x8*)&sA[0][mr * 40 + chb] = av;
    } else {
        const _Float16* src = wt2 + u * BK;
        b0v = *(const f16x8*)(src);      b1v = *(const f16x8*)(src + 8);
        b2v = *(const f16x8*)(src + 16); b3v = *(const f16x8*)(src + 24);
        *(f16x8*)&sB[0][u * 40 + 0]  = b0v;
        *(f16x8*)&sB[0][u * 40 + 8]  = b1v;
        *(f16x8*)&sB[0][u * 40 + 16] = b2v;
        *(f16x8*)&sB[0][u * 40 + 24] = b3v;
    }
    __syncthreads();  // buffer 0 ready

    int ij = 0, cb = 0;
    for (int ks = 0; ks < NKS; ++ks) {
        const int cur = ks & 1, nxt = cur ^ 1;
        const bool have = (ks + 1 < NKS);
        const int ij2 = (ij == 8) ? 0 : ij + 1;
        const int cb2 = (ij == 8) ? cb + 32 : cb;

        // ---- issue next-step loads (hidden under current MFMA) ----
        if (have) {
            if (isA) {
                const int2 o = sTI[ij2 * BM + mr];
                wv = sTW[ij2 * BM + mr];
                const _Float16* p = xb_ + (size_t)o.x * CIN + cb2 + chb;
                const _Float16* q = xb_ + (size_t)o.y * CIN + cb2 + chb;
                p00 = *(const f16x8*)p;  p01 = *(const f16x8*)(p + CIN);
                p10 = *(const f16x8*)q;  p11 = *(const f16x8*)(q + CIN);
            } else {
                const _Float16* src = wt2 + (size_t)(ks + 1) * (COUT * BK) + u * BK;
                b0v = *(const f16x8*)(src);      b1v = *(const f16x8*)(src + 8);
                b2v = *(const f16x8*)(src + 16); b3v = *(const f16x8*)(src + 24);
            }
        }

        // ---- current step: fragments + 8 MFMA (independent of the loads) ----
        f16x8 af[2], bfr[4];
#pragma unroll
        for (int r = 0; r < 2; ++r)
            af[r] = *(const f16x8*)(&sA[cur][(wrow * 32 + r * 16 + l16) * 40 + quad * 8]);
#pragma unroll
        for (int c = 0; c < 4; ++c)
            bfr[c] = *(const f16x8*)(&sB[cur][(wcol * 64 + c * 16 + l16) * 40 + quad * 8]);
#pragma unroll
        for (int r = 0; r < 2; ++r)
#pragma unroll
            for (int c = 0; c < 4; ++c)
                acc[r][c] = __builtin_amdgcn_mfma_f32_16x16x32_f16(
                    af[r], bfr[c], acc[r][c], 0, 0, 0);

        // ---- consume loads, stage buffers for step ks+1 ----
        if (have) {
            if (isA) {
                f16x8 av = p00 * bcast8(wv.x) + p01 * bcast8(wv.y)
                         + p10 * bcast8(wv.z) + p11 * bcast8(wv.w);
                *(f16x8*)&sA[nxt][mr * 40 + chb] = av;
            } else {
                *(f16x8*)&sB[nxt][u * 40 + 0]  = b0v;
                *(f16x8*)&sB[nxt][u * 40 + 8]  = b1v;
                *(f16x8*)&sB[nxt][u * 40 + 16] = b2v;
                *(f16x8*)&sB[nxt][u * 40 + 24] = b3v;
            }
        }

        __syncthreads();   // nxt staged for everyone; cur reads all complete
        ij = ij2; cb = cb2;
    }

    // ---- epilogue: D row=(quad*4+i), col=(lane&15)  [m89-verified layout] ----
#pragma unroll
    for (int c = 0; c < 4; ++c) {
        int n = wcol * 64 + c * 16 + l16;
        float bv = bias[n];
        float* outn = out + (((size_t)(b * COUT + n)) << 15) + sp0;
#pragma unroll
        for (int r = 0; r < 2; ++r) {
            int mbase = wrow * 32 + r * 16 + quad * 4;
            float4 v = make_float4(acc[r][c][0] + bv, acc[r][c][1] + bv,
                                   acc[r][c][2] + bv, acc[r][c][3] + bv);
            *(float4*)(&outn[mbase]) = v;   // 16B aligned
        }
    }
}

// ---------------------------------------------------------------------------
extern "C" void kernel_launch(void* const* d_in, const int* in_sizes, int n_in,
                              void* d_out, int out_size, void* d_ws, size_t ws_size,
                              hipStream_t stream) {
    const float* x    = (const float*)d_in[0];
    const float* w    = (const float*)d_in[1];
    const float* bias = (const float*)d_in[2];
    const float* grid = (const float*)d_in[3];
    float* out = (float*)d_out;

    char* ws = (char*)d_ws;
    int2*     tI  = (int2*)(ws);                    // 294912*8  = 2359296 B
    float4*   tW  = (float4*)(ws + 2359296);        // 294912*16 = 4718592 B
    _Float16* wt2 = (_Float16*)(ws + 7077888);      // 294912*2  =  589824 B
    _Float16* xt  = (_Float16*)(ws + 7667712);      // 16.7M*2   = 33554432 B
                                                    // total 41222144 B

    prep<<<1152 + 1152 + 8192, 256, 0, stream>>>(grid, w, x, tI, tW, wt2, xt);
    sphconv_gemm<<<(4 * HWp) / BM, 512, 0, stream>>>(xt, wt2, bias, tI, tW, out);
}